// Round 6
// baseline (312.718 us; speedup 1.0000x reference)
//
#include <hip/hip_runtime.h>

#define NN    50000   // nodes
#define NHE   50000   // hyperedges
#define NEDGE 320000  // incidence pairs
#define DD    256     // feature dim

#define SB    1024                    // scan elements per block
#define NBLK  ((NN + SB - 1) / SB)    // blocks per segment (NN == NHE) = 49
#define CNTB  ((NEDGE / 4 + 255) / 256)     // 313 blocks, 256 thr, ILP=4
#define FB    ((NEDGE / 4 + 1023) / 1024)   // 79 fill blocks, 1024 thr, ILP=4

typedef float f32x4 __attribute__((ext_vector_type(4)));
typedef short short8 __attribute__((ext_vector_type(8)));

// ---- bf16 helpers (RTNE) ----
static __device__ __forceinline__ unsigned short f2b(float f) {
    union { float f; unsigned u; } c; c.f = f;
    unsigned u = c.u;
    u += 0x7fffu + ((u >> 16) & 1u);
    return (unsigned short)(u >> 16);
}
static __device__ __forceinline__ float b2f_lo(unsigned v) {
    union { unsigned u; float f; } c; c.u = v << 16; return c.f;
}
static __device__ __forceinline__ float b2f_hi(unsigned v) {
    union { unsigned u; float f; } c; c.u = v & 0xffff0000u; return c.f;
}
static __device__ __forceinline__ unsigned pack2(float a, float b) {
    return (unsigned)f2b(a) | ((unsigned)f2b(b) << 16);
}

// async 16B global -> LDS (dest: wave-uniform base + lane*16)
static __device__ __forceinline__ void glds16(const unsigned short* g, unsigned short* l) {
    __builtin_amdgcn_global_load_lds((const __attribute__((address_space(1))) unsigned int*)g,
                                     (__attribute__((address_space(3))) unsigned int*)l,
                                     16, 0, 0);
}

// ---------------- CSR build ----------------
// count + rank capture fused with fp32->bf16 weight conversion. atomicAdd's
// return value IS the edge's slot within its bucket -> fill needs no atomics.
__global__ __launch_bounds__(256) void k_count_cvt(const int* __restrict__ src,
                                                   const int* __restrict__ he,
                                                   int* __restrict__ cnt_n,
                                                   int* __restrict__ cnt_e,
                                                   int* __restrict__ rank_n,
                                                   int* __restrict__ rank_e,
                                                   const float* __restrict__ w1,
                                                   const float* __restrict__ w2,
                                                   unsigned short* __restrict__ o1,
                                                   unsigned short* __restrict__ o2) {
    int bx = blockIdx.x;
    if (bx >= CNTB) {   // 128 trailing blocks: weight conversion
        int t = (bx - CNTB) * 256 + threadIdx.x;   // 0 .. 32767
        const int n4 = DD * DD / 4;
        const float* s = (t < n4) ? w1 : w2;
        unsigned short* d = (t < n4) ? o1 : o2;
        int i = (t < n4) ? t : t - n4;
        float4 v = ((const float4*)s)[i];
        uint2 o;
        o.x = pack2(v.x, v.y);
        o.y = pack2(v.z, v.w);
        ((uint2*)d)[i] = o;
        return;
    }
    int t  = bx * 256 + threadIdx.x;
    int e0 = t * 4;
    if (e0 >= NEDGE) return;
    int4 s = *(const int4*)(src + e0);
    int4 h = *(const int4*)(he + e0);
    int4 rn, re;
    rn.x = atomicAdd(&cnt_n[s.x], 1);
    rn.y = atomicAdd(&cnt_n[s.y], 1);
    rn.z = atomicAdd(&cnt_n[s.z], 1);
    rn.w = atomicAdd(&cnt_n[s.w], 1);
    re.x = atomicAdd(&cnt_e[h.x], 1);
    re.y = atomicAdd(&cnt_e[h.y], 1);
    re.z = atomicAdd(&cnt_e[h.z], 1);
    re.w = atomicAdd(&cnt_e[h.w], 1);
    *(int4*)(rank_n + e0) = rn;
    *(int4*)(rank_e + e0) = re;
}

// single-dispatch scan: each block derives its own base by summing ALL
// preceding counts of its segment (strided int4 reads, <=192 KB, L2-hot),
// then does the usual intra-block exclusive scan. Replaces scan_a+scan_b(+c).
__global__ __launch_bounds__(256) void k_scan(const int* __restrict__ cnt_n,
                                              const int* __restrict__ cnt_e,
                                              int* __restrict__ off_n,
                                              int* __restrict__ off_e) {
    int b   = blockIdx.x;            // 0 .. 2*NBLK-1
    int seg = b / NBLK, lb = b % NBLK;
    const int* cnt = seg ? cnt_e : cnt_n;
    int* off = seg ? off_e : off_n;
    int t = threadIdx.x;

    // ---- base = sum of counts [0, lb*SB)
    int pre = lb * SB;               // multiple of 1024 -> int4-aligned
    int s = 0;
    for (int i = t * 4; i < pre; i += 1024) {
        int4 c = *(const int4*)(cnt + i);
        s += c.x + c.y + c.z + c.w;
    }
    __shared__ int red[256];
    red[t] = s;
    __syncthreads();
    for (int o = 128; o > 0; o >>= 1) {
        if (t < o) red[t] += red[t + o];
        __syncthreads();
    }
    int base = red[0];

    // ---- intra-block exclusive scan of own 1024 counts
    int idx = pre + t * 4;
    int v[4];
    int tsum = 0;
#pragma unroll
    for (int j = 0; j < 4; ++j) {
        v[j] = (idx + j < NN) ? cnt[idx + j] : 0;
        tsum += v[j];
    }
    __shared__ int sc[256];
    sc[t] = tsum;
    __syncthreads();
    for (int o = 1; o < 256; o <<= 1) {
        int val = (t >= o) ? sc[t - o] : 0;
        __syncthreads();
        sc[t] += val;
        __syncthreads();
    }
    int p = base + sc[t] - tsum;
#pragma unroll
    for (int j = 0; j < 4; ++j) {
        if (idx + j < NN) off[idx + j] = p;
        p += v[j];
    }
    if (lb == NBLK - 1 && t == 255) off[NN] = base + sc[255];   // sentinel
}

// -------- B-resident MFMA GEMM body: C[m,n] = sum_k A[m,k]*W[n,k] ----------
// Stage HALF of W (128 rows x 256 k = 64 KB bf16) into LDS ONCE, one barrier,
// then 16 waves per 1024-thr block independently stream A in 16-row chunks
// (wave tile 16x128): 16 upfront A-loads/lane, 64 swizzled ds_reads, 64 MFMAs,
// store. No per-K-step barriers. XOR swizzle (chunk ^= row&7) pre-applied on
// the GLOBAL source of the linear glds write, re-applied on the ds_read.
// bid: even/odd = N-half (adjacent ids share the A chunk-group -> A fetched
// from HBM once), bid>>1 = 16-row chunk-group. 50000 = 3125*16 -> no M tail.
template <bool A32>
static __device__ __forceinline__ void gemm_bres_body(const void* __restrict__ Av,
                                                      const unsigned short* __restrict__ Wb,
                                                      unsigned short* __restrict__ Cb,
                                                      int bid) {
    __shared__ __align__(16) unsigned short Bs[128 * 256];   // 64 KB
    const int t    = threadIdx.x;
    const int lane = t & 63;
    const int wave = t >> 6;            // 0..15
    const int n0   = (bid & 1) * 128;   // N-half

    // ---- stage B half: 4 glds16 per thread, dest linear, source pre-swizzled
#pragma unroll
    for (int q = 0; q < 4; ++q) {
        int row   = q * 32 + wave * 2 + (lane >> 5);   // local B row 0..127
        int chunk = lane & 31;                         // 16B chunk within row
        glds16(Wb + (size_t)(n0 + row) * DD + ((chunk ^ (row & 7)) * 8),
               Bs + q * 8192 + wave * 512);            // elem offs = bytes/2
    }
    __syncthreads();   // the ONLY barrier

    const int fr = lane & 15;
    const int fq = lane >> 4;
    int chunk = (bid >> 1) * 16 + wave;   // 16-row M chunk id
    if (chunk * 16 >= NN) return;         // post-barrier exit: safe
    int m0 = chunk * 16;

    f32x4 acc[8] = {};
    short8 af[8];
    if (A32) {
        const float* p = (const float*)Av + (size_t)(m0 + fr) * DD + fq * 8;
#pragma unroll
        for (int kc = 0; kc < 8; ++kc) {
            const float* pp = p + kc * 32;
            float4 f0 = ((const float4*)pp)[0];
            float4 f1 = ((const float4*)pp)[1];
            uint4 u;
            u.x = pack2(f0.x, f0.y); u.y = pack2(f0.z, f0.w);
            u.z = pack2(f1.x, f1.y); u.w = pack2(f1.z, f1.w);
            af[kc] = *(short8*)&u;
        }
    } else {
        const unsigned short* p = (const unsigned short*)Av + (size_t)(m0 + fr) * DD + fq * 8;
#pragma unroll
        for (int kc = 0; kc < 8; ++kc)
            af[kc] = *(const short8*)(p + kc * 32);
    }

#pragma unroll
    for (int kc = 0; kc < 8; ++kc) {
#pragma unroll
        for (int nt = 0; nt < 8; ++nt) {
            int r  = nt * 16 + fr;
            int ch = (kc * 4 + fq) ^ (fr & 7);
            short8 bf = *(const short8*)(Bs + r * 256 + ch * 8);
            acc[nt] = __builtin_amdgcn_mfma_f32_16x16x32_bf16(af[kc], bf, acc[nt], 0, 0, 0);
        }
    }

    // C/D layout: col = lane&15, row = quad*4 + reg
#pragma unroll
    for (int nt = 0; nt < 8; ++nt)
#pragma unroll
        for (int i = 0; i < 4; ++i)
            Cb[(size_t)(m0 + fq * 4 + i) * DD + n0 + nt * 16 + fr] = f2b(acc[nt][i]);
}

// heterogeneous dispatch: atomic-free CSR fill (79 blocks, ranks captured in
// k_count_cvt) runs concurrently with GEMM1 (392 blocks) -- fill hides under
// the GEMM and adj_* are complete when the dispatch retires (stream order).
__global__ __launch_bounds__(1024) void k_fill_gemm1(const int* __restrict__ src,
                                                     const int* __restrict__ he,
                                                     const int* __restrict__ off_n,
                                                     const int* __restrict__ off_e,
                                                     const int* __restrict__ rank_n,
                                                     const int* __restrict__ rank_e,
                                                     int* __restrict__ adj_n,
                                                     int* __restrict__ adj_e,
                                                     const float* __restrict__ x,
                                                     const unsigned short* __restrict__ w1b,
                                                     unsigned short* __restrict__ B1) {
    int bx = blockIdx.x;
    if (bx < FB) {
        int t  = bx * 1024 + threadIdx.x;
        int e0 = t * 4;
        if (e0 >= NEDGE) return;
        int4 s  = *(const int4*)(src + e0);
        int4 h  = *(const int4*)(he + e0);
        int4 rn = *(const int4*)(rank_n + e0);
        int4 re = *(const int4*)(rank_e + e0);
        int on0 = off_n[s.x], on1 = off_n[s.y], on2 = off_n[s.z], on3 = off_n[s.w];
        int oe0 = off_e[h.x], oe1 = off_e[h.y], oe2 = off_e[h.z], oe3 = off_e[h.w];
        adj_n[on0 + rn.x] = h.x;
        adj_n[on1 + rn.y] = h.y;
        adj_n[on2 + rn.z] = h.z;
        adj_n[on3 + rn.w] = h.w;
        adj_e[oe0 + re.x] = s.x;
        adj_e[oe1 + re.y] = s.y;
        adj_e[oe2 + re.z] = s.z;
        adj_e[oe3 + re.w] = s.w;
        return;
    }
    gemm_bres_body<true>((const void*)x, w1b, B1, bx - FB);
}

__global__ __launch_bounds__(1024) void k_gemm2(const unsigned short* __restrict__ Av,
                                                const unsigned short* __restrict__ Wb,
                                                unsigned short* __restrict__ Cb) {
    gemm_bres_body<false>((const void*)Av, Wb, Cb, blockIdx.x);
}

// ---------------- gather core: 32 lanes per row, uint4 (8 bf16) per lane ------
// (proven round-2 form: unroll-8 neighbor batches, mean degree 6.4)
static __device__ __forceinline__ void acc8(float* a, uint4 v) {
    a[0] += b2f_lo(v.x); a[1] += b2f_hi(v.x);
    a[2] += b2f_lo(v.y); a[3] += b2f_hi(v.y);
    a[4] += b2f_lo(v.z); a[5] += b2f_hi(v.z);
    a[6] += b2f_lo(v.w); a[7] += b2f_hi(v.w);
}
static __device__ __forceinline__ void gather8(const unsigned short* __restrict__ srcb,
                                               const int* __restrict__ adj,
                                               int b, int e, int sl, float* a) {
#pragma unroll
    for (int i = 0; i < 8; ++i) a[i] = 0.f;
    for (int i = b; i < e; i += 8) {
        int g0 = adj[i];
        int g[8];
        g[0] = g0;
#pragma unroll
        for (int j = 1; j < 8; ++j) g[j] = (i + j < e) ? adj[i + j] : g0;
        uint4 v[8];
#pragma unroll
        for (int j = 0; j < 8; ++j)
            v[j] = *(const uint4*)(srcb + (size_t)g[j] * DD + sl * 8);
        acc8(a, v[0]);
#pragma unroll
        for (int j = 1; j < 8; ++j)
            if (i + j < e) acc8(a, v[j]);
    }
}

__global__ __launch_bounds__(256) void k_gather_edge_b(const unsigned short* __restrict__ xw,
                                                       unsigned short* __restrict__ ef,
                                                       const int* __restrict__ off,
                                                       const int* __restrict__ adj) {
    int tid = blockIdx.x * 256 + threadIdx.x;
    int w = tid >> 5;           // one 32-lane half-wave per row
    int sl = tid & 31;
    if (w >= NHE) return;
    int b = off[w], e = off[w + 1];
    float a[8];
    gather8(xw, adj, b, e, sl, a);
    float sc = (e > b) ? 1.f / (float)(e - b) : 0.f;
    uint4 o;
    o.x = pack2(a[0] * sc, a[1] * sc);
    o.y = pack2(a[2] * sc, a[3] * sc);
    o.z = pack2(a[4] * sc, a[5] * sc);
    o.w = pack2(a[6] * sc, a[7] * sc);
    *(uint4*)(ef + (size_t)w * DD + sl * 8) = o;
}

__global__ __launch_bounds__(256) void k_gather_node_mid_b(const unsigned short* __restrict__ ef,
                                                           unsigned short* __restrict__ h,
                                                           const int* __restrict__ off,
                                                           const int* __restrict__ adj,
                                                           const float* __restrict__ bias,
                                                           const float* __restrict__ aP) {
    int tid = blockIdx.x * 256 + threadIdx.x;
    int w = tid >> 5;
    int sl = tid & 31;
    if (w >= NN) return;
    int b = off[w], e = off[w + 1];
    float a[8];
    gather8(ef, adj, b, e, sl, a);
    float sc = (e > b) ? 1.f / (float)(e - b) : 0.f;
    float al = *aP;
    float4 bb0 = ((const float4*)bias)[sl * 2];
    float4 bb1 = ((const float4*)bias)[sl * 2 + 1];
    float r[8];
    r[0] = a[0] * sc + bb0.x; r[1] = a[1] * sc + bb0.y;
    r[2] = a[2] * sc + bb0.z; r[3] = a[3] * sc + bb0.w;
    r[4] = a[4] * sc + bb1.x; r[5] = a[5] * sc + bb1.y;
    r[6] = a[6] * sc + bb1.z; r[7] = a[7] * sc + bb1.w;
#pragma unroll
    for (int i = 0; i < 8; ++i) r[i] = (r[i] >= 0.f) ? r[i] : al * r[i];
    uint4 o;
    o.x = pack2(r[0], r[1]);
    o.y = pack2(r[2], r[3]);
    o.z = pack2(r[4], r[5]);
    o.w = pack2(r[6], r[7]);
    *(uint4*)(h + (size_t)w * DD + sl * 8) = o;
}

__global__ __launch_bounds__(256) void k_gather_node_final_b(const unsigned short* __restrict__ ef,
                                                             const float* __restrict__ x,
                                                             float* __restrict__ out,
                                                             const int* __restrict__ off,
                                                             const int* __restrict__ adj,
                                                             const float* __restrict__ bias,
                                                             const float* __restrict__ aP) {
    int tid = blockIdx.x * 256 + threadIdx.x;
    int w = tid >> 5;
    int sl = tid & 31;
    if (w >= NN) return;
    int b = off[w], e = off[w + 1];
    float a[8];
    gather8(ef, adj, b, e, sl, a);
    float sc = (e > b) ? 1.f / (float)(e - b) : 0.f;
    float al = *aP;
    float4 bb0 = ((const float4*)bias)[sl * 2];
    float4 bb1 = ((const float4*)bias)[sl * 2 + 1];
    const float* xp = x + (size_t)w * DD + sl * 8;
    float4 xv0 = *(const float4*)xp;
    float4 xv1 = *(const float4*)(xp + 4);
    float r[8];
    r[0] = a[0] * sc + bb0.x + xv0.x; r[1] = a[1] * sc + bb0.y + xv0.y;
    r[2] = a[2] * sc + bb0.z + xv0.z; r[3] = a[3] * sc + bb0.w + xv0.w;
    r[4] = a[4] * sc + bb1.x + xv1.x; r[5] = a[5] * sc + bb1.y + xv1.y;
    r[6] = a[6] * sc + bb1.z + xv1.z; r[7] = a[7] * sc + bb1.w + xv1.w;
#pragma unroll
    for (int i = 0; i < 8; ++i) r[i] = (r[i] >= 0.f) ? r[i] : al * r[i];
    float* op = out + (size_t)w * DD + sl * 8;
    *(float4*)op = make_float4(r[0], r[1], r[2], r[3]);
    *(float4*)(op + 4) = make_float4(r[4], r[5], r[6], r[7]);
}

extern "C" void kernel_launch(void* const* d_in, const int* in_sizes, int n_in,
                              void* d_out, int out_size, void* d_ws, size_t ws_size,
                              hipStream_t stream) {
    const float* x       = (const float*)d_in[0];
    const float* W1      = (const float*)d_in[1];
    const float* b1      = (const float*)d_in[2];
    const float* W2      = (const float*)d_in[3];
    const float* b2      = (const float*)d_in[4];
    const float* prelu_a = (const float*)d_in[5];
    const int*   hei     = (const int*)d_in[6];
    const int* idx_src = hei;          // hei[0,:] node indices
    const int* idx_he  = hei + NEDGE;  // hei[1,:] hyperedge indices

    float* out = (float*)d_out;
    unsigned short* B1 = (unsigned short*)d_ws;           // [NN*DD] bf16
    unsigned short* B2 = B1 + (size_t)NN * DD;            // [NN*DD] bf16
    int* off_n  = (int*)(B2 + (size_t)NN * DD);           // NN+1
    int* off_e  = off_n + NN + 1;                         // NHE+1
    int* cnt_n  = off_e + NHE + 1;                        // NN
    int* cnt_e  = cnt_n + NN;                             // NHE
    int* adj_n  = cnt_e + NHE;                            // NEDGE
    int* adj_e  = adj_n + NEDGE;                          // NEDGE
    int* rank_n = adj_e + NEDGE;                          // NEDGE
    int* rank_e = rank_n + NEDGE;                         // NEDGE
    // d_out doubles as bf16 weight storage until the final kernel
    unsigned short* w1b = (unsigned short*)d_out;         // [DD*DD]
    unsigned short* w2b = w1b + DD * DD;                  // [DD*DD]

    const int gblocks = (NN * 32 + 255) / 256;            // 6250: 32 lanes/row
    const int gemmb   = 2 * ((NN / 16 + 15) / 16);        // 392 GEMM blocks

    // ---- CSR build + weight cvt (memset -> count+cvt -> single-pass scan) ----
    hipMemsetAsync(cnt_n, 0, sizeof(int) * (NN + NHE), stream);
    k_count_cvt<<<CNTB + 128, 256, 0, stream>>>(idx_src, idx_he, cnt_n, cnt_e,
                                                rank_n, rank_e, W1, W2, w1b, w2b);
    k_scan<<<2 * NBLK, 256, 0, stream>>>(cnt_n, cnt_e, off_n, off_e);

    // ---- fill (CSR) || GEMM1 in one dispatch; then layer-1 gathers ----
    k_fill_gemm1<<<FB + gemmb, 1024, 0, stream>>>(idx_src, idx_he, off_n, off_e,
                                                  rank_n, rank_e, adj_n, adj_e,
                                                  x, w1b, B1);                   // B1 = bf16(x@W1^T)
    k_gather_edge_b<<<gblocks, 256, 0, stream>>>(B1, B2, off_e, adj_e);          // B2 = ef1
    k_gather_node_mid_b<<<gblocks, 256, 0, stream>>>(B2, B1, off_n, adj_n, b1, prelu_a); // B1 = h1

    // ---- layer 2 ----
    k_gemm2<<<gemmb, 1024, 0, stream>>>(B1, w2b, B2);                            // B2 = bf16(h1@W2^T)
    k_gather_edge_b<<<gblocks, 256, 0, stream>>>(B2, B1, off_e, adj_e);          // B1 = ef2
    k_gather_node_final_b<<<gblocks, 256, 0, stream>>>(B1, x, out, off_n, adj_n, b2, prelu_a);
}

// Round 7
// 306.417 us; speedup vs baseline: 1.0206x; 1.0206x over previous
//
#include <hip/hip_runtime.h>

#define NN    50000   // nodes
#define NHE   50000   // hyperedges
#define NEDGE 320000  // incidence pairs
#define DD    256     // feature dim

#define SB    1024                    // scan elements per block
#define NBLK  ((NN + SB - 1) / SB)    // blocks per segment (NN == NHE) = 49
#define CNTB  ((NEDGE / 4 + 255) / 256)     // 313 blocks, 256 thr, ILP=4
#define XCB   (NN * DD / 2048)              // 6250 x->bf16 cvt blocks

typedef float f32x4 __attribute__((ext_vector_type(4)));
typedef short short8 __attribute__((ext_vector_type(8)));

// ---- bf16 helpers (RTNE) ----
static __device__ __forceinline__ unsigned short f2b(float f) {
    union { float f; unsigned u; } c; c.f = f;
    unsigned u = c.u;
    u += 0x7fffu + ((u >> 16) & 1u);
    return (unsigned short)(u >> 16);
}
static __device__ __forceinline__ float b2f_lo(unsigned v) {
    union { unsigned u; float f; } c; c.u = v << 16; return c.f;
}
static __device__ __forceinline__ float b2f_hi(unsigned v) {
    union { unsigned u; float f; } c; c.u = v & 0xffff0000u; return c.f;
}
static __device__ __forceinline__ unsigned pack2(float a, float b) {
    return (unsigned)f2b(a) | ((unsigned)f2b(b) << 16);
}

// async 16B global -> LDS (dest: wave-uniform base + lane*16)
static __device__ __forceinline__ void glds16(const unsigned short* g, unsigned short* l) {
    __builtin_amdgcn_global_load_lds((const __attribute__((address_space(1))) unsigned int*)g,
                                     (__attribute__((address_space(3))) unsigned int*)l,
                                     16, 0, 0);
}

// ---------------- CSR build + conversions (one dispatch) ----------------
// blocks [0, CNTB):           edge count + rank capture (atomicAdd return = slot)
// blocks [CNTB, CNTB+128):    W1/W2 fp32 -> bf16
// blocks [CNTB+128, +XCB):    x fp32 -> bf16 (rides the idle HBM while the
//                             atomic blocks are latency-bound)
__global__ __launch_bounds__(256) void k_count_cvt(const int* __restrict__ src,
                                                   const int* __restrict__ he,
                                                   int* __restrict__ cnt_n,
                                                   int* __restrict__ cnt_e,
                                                   int* __restrict__ rank_n,
                                                   int* __restrict__ rank_e,
                                                   const float* __restrict__ w1,
                                                   const float* __restrict__ w2,
                                                   unsigned short* __restrict__ o1,
                                                   unsigned short* __restrict__ o2,
                                                   const float* __restrict__ x,
                                                   unsigned short* __restrict__ xb) {
    int bx = blockIdx.x;
    if (bx >= CNTB + 128) {   // x conversion: 8 floats/thread
        int t = (bx - CNTB - 128) * 256 + threadIdx.x;
        const float4* p = (const float4*)x + (size_t)t * 2;
        float4 a = p[0], b = p[1];
        uint4 o;
        o.x = pack2(a.x, a.y); o.y = pack2(a.z, a.w);
        o.z = pack2(b.x, b.y); o.w = pack2(b.z, b.w);
        ((uint4*)xb)[t] = o;
        return;
    }
    if (bx >= CNTB) {   // weight conversion
        int t = (bx - CNTB) * 256 + threadIdx.x;   // 0 .. 32767
        const int n4 = DD * DD / 4;
        const float* s = (t < n4) ? w1 : w2;
        unsigned short* d = (t < n4) ? o1 : o2;
        int i = (t < n4) ? t : t - n4;
        float4 v = ((const float4*)s)[i];
        uint2 o;
        o.x = pack2(v.x, v.y);
        o.y = pack2(v.z, v.w);
        ((uint2*)d)[i] = o;
        return;
    }
    int t  = bx * 256 + threadIdx.x;
    int e0 = t * 4;
    if (e0 >= NEDGE) return;
    int4 s = *(const int4*)(src + e0);
    int4 h = *(const int4*)(he + e0);
    int4 rn, re;
    rn.x = atomicAdd(&cnt_n[s.x], 1);
    rn.y = atomicAdd(&cnt_n[s.y], 1);
    rn.z = atomicAdd(&cnt_n[s.z], 1);
    rn.w = atomicAdd(&cnt_n[s.w], 1);
    re.x = atomicAdd(&cnt_e[h.x], 1);
    re.y = atomicAdd(&cnt_e[h.y], 1);
    re.z = atomicAdd(&cnt_e[h.z], 1);
    re.w = atomicAdd(&cnt_e[h.w], 1);
    *(int4*)(rank_n + e0) = rn;
    *(int4*)(rank_e + e0) = re;
}

// single-dispatch scan: each block derives its own base by summing ALL
// preceding counts of its segment (strided int4 reads, <=192 KB, L2-hot),
// then does the usual intra-block exclusive scan.
__global__ __launch_bounds__(256) void k_scan(const int* __restrict__ cnt_n,
                                              const int* __restrict__ cnt_e,
                                              int* __restrict__ off_n,
                                              int* __restrict__ off_e) {
    int b   = blockIdx.x;            // 0 .. 2*NBLK-1
    int seg = b / NBLK, lb = b % NBLK;
    const int* cnt = seg ? cnt_e : cnt_n;
    int* off = seg ? off_e : off_n;
    int t = threadIdx.x;

    // ---- base = sum of counts [0, lb*SB)
    int pre = lb * SB;               // multiple of 1024 -> int4-aligned
    int s = 0;
    for (int i = t * 4; i < pre; i += 1024) {
        int4 c = *(const int4*)(cnt + i);
        s += c.x + c.y + c.z + c.w;
    }
    __shared__ int red[256];
    red[t] = s;
    __syncthreads();
    for (int o = 128; o > 0; o >>= 1) {
        if (t < o) red[t] += red[t + o];
        __syncthreads();
    }
    int base = red[0];

    // ---- intra-block exclusive scan of own 1024 counts
    int idx = pre + t * 4;
    int v[4];
    int tsum = 0;
#pragma unroll
    for (int j = 0; j < 4; ++j) {
        v[j] = (idx + j < NN) ? cnt[idx + j] : 0;
        tsum += v[j];
    }
    __shared__ int sc[256];
    sc[t] = tsum;
    __syncthreads();
    for (int o = 1; o < 256; o <<= 1) {
        int val = (t >= o) ? sc[t - o] : 0;
        __syncthreads();
        sc[t] += val;
        __syncthreads();
    }
    int p = base + sc[t] - tsum;
#pragma unroll
    for (int j = 0; j < 4; ++j) {
        if (idx + j < NN) off[idx + j] = p;
        p += v[j];
    }
    if (lb == NBLK - 1 && t == 255) off[NN] = base + sc[255];   // sentinel
}

// atomic-free fill (ranks captured in k_count_cvt). ILP=4 edges/thread.
__global__ __launch_bounds__(256) void k_fill(const int* __restrict__ src,
                                              const int* __restrict__ he,
                                              const int* __restrict__ off_n,
                                              const int* __restrict__ off_e,
                                              const int* __restrict__ rank_n,
                                              const int* __restrict__ rank_e,
                                              int* __restrict__ adj_n,
                                              int* __restrict__ adj_e) {
    int t  = blockIdx.x * 256 + threadIdx.x;
    int e0 = t * 4;
    if (e0 >= NEDGE) return;
    int4 s  = *(const int4*)(src + e0);
    int4 h  = *(const int4*)(he + e0);
    int4 rn = *(const int4*)(rank_n + e0);
    int4 re = *(const int4*)(rank_e + e0);
    int on0 = off_n[s.x], on1 = off_n[s.y], on2 = off_n[s.z], on3 = off_n[s.w];
    int oe0 = off_e[h.x], oe1 = off_e[h.y], oe2 = off_e[h.z], oe3 = off_e[h.w];
    adj_n[on0 + rn.x] = h.x;
    adj_n[on1 + rn.y] = h.y;
    adj_n[on2 + rn.z] = h.z;
    adj_n[on3 + rn.w] = h.w;
    adj_e[oe0 + re.x] = s.x;
    adj_e[oe1 + re.y] = s.y;
    adj_e[oe2 + re.z] = s.z;
    adj_e[oe3 + re.w] = s.w;
}

// -------- B-resident MFMA GEMM: C[m,n] = sum_k A[m,k]*W[n,k], A bf16 --------
// Stage HALF of W (128 x 256 = 64 KB bf16) into LDS ONCE, one barrier, then 16
// waves per 1024-thr block independently stream A in 16-row chunks (wave tile
// 16x128). A fragments (af[8] = 32 VGPR) are PREFETCHED BEFORE the barrier so
// their HBM latency hides under B staging; after the barrier each wave runs
// 64 swizzled ds_reads + 64 MFMAs with no memory stalls, then stores. XOR
// swizzle (chunk ^= row&7) pre-applied on the GLOBAL source of the linear
// glds write, re-applied on the ds_read. bid even/odd = N-half (adjacent ids
// share the A chunk-group). 50000 = 3125*16 -> no M tail.
__global__ __launch_bounds__(1024) void k_gemm(const unsigned short* __restrict__ Av,
                                               const unsigned short* __restrict__ Wb,
                                               unsigned short* __restrict__ Cb) {
    __shared__ __align__(16) unsigned short Bs[128 * 256];   // 64 KB
    const int t    = threadIdx.x;
    const int lane = t & 63;
    const int wave = t >> 6;                  // 0..15
    const int n0   = (blockIdx.x & 1) * 128;  // N-half
    const int fr   = lane & 15;
    const int fq   = lane >> 4;

    // ---- stage B half: 4 glds16 per thread, dest linear, source pre-swizzled
#pragma unroll
    for (int q = 0; q < 4; ++q) {
        int row   = q * 32 + wave * 2 + (lane >> 5);   // local B row 0..127
        int chunk = lane & 31;                         // 16B chunk within row
        glds16(Wb + (size_t)(n0 + row) * DD + ((chunk ^ (row & 7)) * 8),
               Bs + q * 8192 + wave * 512);            // elem offs = bytes/2
    }

    // ---- prefetch own A fragments (overlaps B staging + barrier drain)
    int mchunk = (blockIdx.x >> 1) * 16 + wave;   // 16-row M chunk id
    int m0  = mchunk * 16;
    int m0c = (m0 + 16 <= NN) ? m0 : NN - 16;     // clamped load base
    short8 af[8];
    {
        const unsigned short* p = Av + (size_t)(m0c + fr) * DD + fq * 8;
#pragma unroll
        for (int kc = 0; kc < 8; ++kc)
            af[kc] = *(const short8*)(p + kc * 32);
    }

    __syncthreads();   // the ONLY barrier (drains glds + A loads)
    if (m0 >= NN) return;

    f32x4 acc[8] = {};
#pragma unroll
    for (int kc = 0; kc < 8; ++kc) {
#pragma unroll
        for (int nt = 0; nt < 8; ++nt) {
            int r  = nt * 16 + fr;
            int ch = (kc * 4 + fq) ^ (fr & 7);
            short8 bf = *(const short8*)(Bs + r * 256 + ch * 8);
            acc[nt] = __builtin_amdgcn_mfma_f32_16x16x32_bf16(af[kc], bf, acc[nt], 0, 0, 0);
        }
    }

    // C/D layout: col = lane&15, row = quad*4 + reg
#pragma unroll
    for (int nt = 0; nt < 8; ++nt)
#pragma unroll
        for (int i = 0; i < 4; ++i)
            Cb[(size_t)(m0 + fq * 4 + i) * DD + n0 + nt * 16 + fr] = f2b(acc[nt][i]);
}

// ---------------- gather core: 32 lanes per row, uint4 (8 bf16) per lane ------
// (proven round-2 form: unroll-8 neighbor batches, mean degree 6.4)
static __device__ __forceinline__ void acc8(float* a, uint4 v) {
    a[0] += b2f_lo(v.x); a[1] += b2f_hi(v.x);
    a[2] += b2f_lo(v.y); a[3] += b2f_hi(v.y);
    a[4] += b2f_lo(v.z); a[5] += b2f_hi(v.z);
    a[6] += b2f_lo(v.w); a[7] += b2f_hi(v.w);
}
static __device__ __forceinline__ void gather8(const unsigned short* __restrict__ srcb,
                                               const int* __restrict__ adj,
                                               int b, int e, int sl, float* a) {
#pragma unroll
    for (int i = 0; i < 8; ++i) a[i] = 0.f;
    for (int i = b; i < e; i += 8) {
        int g0 = adj[i];
        int g[8];
        g[0] = g0;
#pragma unroll
        for (int j = 1; j < 8; ++j) g[j] = (i + j < e) ? adj[i + j] : g0;
        uint4 v[8];
#pragma unroll
        for (int j = 0; j < 8; ++j)
            v[j] = *(const uint4*)(srcb + (size_t)g[j] * DD + sl * 8);
        acc8(a, v[0]);
#pragma unroll
        for (int j = 1; j < 8; ++j)
            if (i + j < e) acc8(a, v[j]);
    }
}

__global__ __launch_bounds__(256) void k_gather_edge_b(const unsigned short* __restrict__ xw,
                                                       unsigned short* __restrict__ ef,
                                                       const int* __restrict__ off,
                                                       const int* __restrict__ adj) {
    int tid = blockIdx.x * 256 + threadIdx.x;
    int w = tid >> 5;           // one 32-lane half-wave per row
    int sl = tid & 31;
    if (w >= NHE) return;
    int b = off[w], e = off[w + 1];
    float a[8];
    gather8(xw, adj, b, e, sl, a);
    float sc = (e > b) ? 1.f / (float)(e - b) : 0.f;
    uint4 o;
    o.x = pack2(a[0] * sc, a[1] * sc);
    o.y = pack2(a[2] * sc, a[3] * sc);
    o.z = pack2(a[4] * sc, a[5] * sc);
    o.w = pack2(a[6] * sc, a[7] * sc);
    *(uint4*)(ef + (size_t)w * DD + sl * 8) = o;
}

__global__ __launch_bounds__(256) void k_gather_node_mid_b(const unsigned short* __restrict__ ef,
                                                           unsigned short* __restrict__ h,
                                                           const int* __restrict__ off,
                                                           const int* __restrict__ adj,
                                                           const float* __restrict__ bias,
                                                           const float* __restrict__ aP) {
    int tid = blockIdx.x * 256 + threadIdx.x;
    int w = tid >> 5;
    int sl = tid & 31;
    if (w >= NN) return;
    int b = off[w], e = off[w + 1];
    float a[8];
    gather8(ef, adj, b, e, sl, a);
    float sc = (e > b) ? 1.f / (float)(e - b) : 0.f;
    float al = *aP;
    float4 bb0 = ((const float4*)bias)[sl * 2];
    float4 bb1 = ((const float4*)bias)[sl * 2 + 1];
    float r[8];
    r[0] = a[0] * sc + bb0.x; r[1] = a[1] * sc + bb0.y;
    r[2] = a[2] * sc + bb0.z; r[3] = a[3] * sc + bb0.w;
    r[4] = a[4] * sc + bb1.x; r[5] = a[5] * sc + bb1.y;
    r[6] = a[6] * sc + bb1.z; r[7] = a[7] * sc + bb1.w;
#pragma unroll
    for (int i = 0; i < 8; ++i) r[i] = (r[i] >= 0.f) ? r[i] : al * r[i];
    uint4 o;
    o.x = pack2(r[0], r[1]);
    o.y = pack2(r[2], r[3]);
    o.z = pack2(r[4], r[5]);
    o.w = pack2(r[6], r[7]);
    *(uint4*)(h + (size_t)w * DD + sl * 8) = o;
}

__global__ __launch_bounds__(256) void k_gather_node_final_b(const unsigned short* __restrict__ ef,
                                                             const float* __restrict__ x,
                                                             float* __restrict__ out,
                                                             const int* __restrict__ off,
                                                             const int* __restrict__ adj,
                                                             const float* __restrict__ bias,
                                                             const float* __restrict__ aP) {
    int tid = blockIdx.x * 256 + threadIdx.x;
    int w = tid >> 5;
    int sl = tid & 31;
    if (w >= NN) return;
    int b = off[w], e = off[w + 1];
    float a[8];
    gather8(ef, adj, b, e, sl, a);
    float sc = (e > b) ? 1.f / (float)(e - b) : 0.f;
    float al = *aP;
    float4 bb0 = ((const float4*)bias)[sl * 2];
    float4 bb1 = ((const float4*)bias)[sl * 2 + 1];
    const float* xp = x + (size_t)w * DD + sl * 8;
    float4 xv0 = *(const float4*)xp;
    float4 xv1 = *(const float4*)(xp + 4);
    float r[8];
    r[0] = a[0] * sc + bb0.x + xv0.x; r[1] = a[1] * sc + bb0.y + xv0.y;
    r[2] = a[2] * sc + bb0.z + xv0.z; r[3] = a[3] * sc + bb0.w + xv0.w;
    r[4] = a[4] * sc + bb1.x + xv1.x; r[5] = a[5] * sc + bb1.y + xv1.y;
    r[6] = a[6] * sc + bb1.z + xv1.z; r[7] = a[7] * sc + bb1.w + xv1.w;
#pragma unroll
    for (int i = 0; i < 8; ++i) r[i] = (r[i] >= 0.f) ? r[i] : al * r[i];
    float* op = out + (size_t)w * DD + sl * 8;
    *(float4*)op = make_float4(r[0], r[1], r[2], r[3]);
    *(float4*)(op + 4) = make_float4(r[4], r[5], r[6], r[7]);
}

extern "C" void kernel_launch(void* const* d_in, const int* in_sizes, int n_in,
                              void* d_out, int out_size, void* d_ws, size_t ws_size,
                              hipStream_t stream) {
    const float* x       = (const float*)d_in[0];
    const float* W1      = (const float*)d_in[1];
    const float* b1      = (const float*)d_in[2];
    const float* W2      = (const float*)d_in[3];
    const float* b2      = (const float*)d_in[4];
    const float* prelu_a = (const float*)d_in[5];
    const int*   hei     = (const int*)d_in[6];
    const int* idx_src = hei;          // hei[0,:] node indices
    const int* idx_he  = hei + NEDGE;  // hei[1,:] hyperedge indices

    float* out = (float*)d_out;
    unsigned short* B1 = (unsigned short*)d_ws;           // [NN*DD] bf16
    unsigned short* B2 = B1 + (size_t)NN * DD;            // [NN*DD] bf16
    int* off_n  = (int*)(B2 + (size_t)NN * DD);           // NN+1
    int* off_e  = off_n + NN + 1;                         // NHE+1
    int* cnt_n  = off_e + NHE + 1;                        // NN
    int* cnt_e  = cnt_n + NN;                             // NHE
    int* adj_n  = cnt_e + NHE;                            // NEDGE
    int* adj_e  = adj_n + NEDGE;                          // NEDGE
    int* rank_n = adj_e + NEDGE;                          // NEDGE
    int* rank_e = rank_n + NEDGE;                         // NEDGE
    // d_out doubles as bf16 weight storage until the final kernel
    unsigned short* w1b = (unsigned short*)d_out;         // [DD*DD]
    unsigned short* w2b = w1b + DD * DD;                  // [DD*DD]

    const int gblocks = (NN * 32 + 255) / 256;            // 6250: 32 lanes/row
    const int gemmb   = 2 * (NN / 16 / 16 + 1);           // 2*196 = 392 blocks

    // ---- CSR build + x/W conversions (memset -> count+cvt -> scan -> fill) ----
    hipMemsetAsync(cnt_n, 0, sizeof(int) * (NN + NHE), stream);
    k_count_cvt<<<CNTB + 128 + XCB, 256, 0, stream>>>(idx_src, idx_he, cnt_n, cnt_e,
                                                      rank_n, rank_e, W1, W2, w1b, w2b,
                                                      x, B2);                    // B2 = bf16(x)
    k_scan<<<2 * NBLK, 256, 0, stream>>>(cnt_n, cnt_e, off_n, off_e);
    k_fill<<<CNTB, 256, 0, stream>>>(idx_src, idx_he, off_n, off_e,
                                     rank_n, rank_e, adj_n, adj_e);

    // ---- layer 1 ----
    k_gemm<<<gemmb, 1024, 0, stream>>>(B2, w1b, B1);                             // B1 = bf16(x@W1^T)
    k_gather_edge_b<<<gblocks, 256, 0, stream>>>(B1, B2, off_e, adj_e);          // B2 = ef1 (xb16 dead)
    k_gather_node_mid_b<<<gblocks, 256, 0, stream>>>(B2, B1, off_n, adj_n, b1, prelu_a); // B1 = h1

    // ---- layer 2 ----
    k_gemm<<<gemmb, 1024, 0, stream>>>(B1, w2b, B2);                             // B2 = bf16(h1@W2^T)
    k_gather_edge_b<<<gblocks, 256, 0, stream>>>(B2, B1, off_e, adj_e);          // B1 = ef2
    k_gather_node_final_b<<<gblocks, 256, 0, stream>>>(B1, x, out, off_n, adj_n, b2, prelu_a);
}